// Round 8
// baseline (15303.514 us; speedup 1.0000x reference)
//
#include <hip/hip_runtime.h>

#define U_ 1024
#define B_ 64
#define T_ 256
#define DIN_ 128
#define BT_ (B_*T_)
#define G_ 1024  // 4 blocks/CU by launch_bounds(256,4); plain launch (coop validator rejects >256)

typedef __attribute__((ext_vector_type(4))) float f32x4;
typedef __attribute__((ext_vector_type(8))) short s16x8;
typedef __attribute__((ext_vector_type(4))) unsigned short u16x4;
typedef unsigned long long u64;

union U64F2 { u64 q; float f[2]; };
union U64H4 { u64 q; unsigned short h[4]; };

__device__ inline unsigned short f2bf(float x){
  unsigned u = __float_as_uint(x);
  u += 0x7FFFu + ((u >> 16) & 1u);
  return (unsigned short)(u >> 16);
}
__device__ inline float bf2f(unsigned short b){ return __uint_as_float(((unsigned)b) << 16); }
__device__ inline float fast_rcp(float x){ return __builtin_amdgcn_rcpf(x); }
__device__ inline float fast_tanh(float x){
  float e = __expf(2.0f * x);
  return 1.0f - 2.0f * fast_rcp(e + 1.0f);
}
__device__ inline float fast_sig(float x){
  return fast_rcp(1.0f + __expf(-x));
}

// sc1 (agent-coherent, L3-point) accessors — no fences anywhere.
__device__ inline u64 ald64(const u64* p){
  return __hip_atomic_load((u64*)p, __ATOMIC_RELAXED, __HIP_MEMORY_SCOPE_AGENT);
}
__device__ inline void ast64(u64* p, u64 v){
  __hip_atomic_store(p, v, __ATOMIC_RELAXED, __HIP_MEMORY_SCOPE_AGENT);
}
__device__ inline float aldf(const float* p){
  return __hip_atomic_load((float*)p, __ATOMIC_RELAXED, __HIP_MEMORY_SCOPE_AGENT);
}
__device__ inline void astf(float* p, float v){
  __hip_atomic_store(p, v, __ATOMIC_RELAXED, __HIP_MEMORY_SCOPE_AGENT);
}
__device__ inline s16x8 frag_ald(const u64* p){
  u64 a = ald64(p), b = ald64(p + 1);
  union { u64 q[2]; s16x8 v; } x; x.q[0] = a; x.q[1] = b; return x.v;
}

// ---------------- init ----------------
__global__ void init_kernel(float* c, unsigned short* hb0, unsigned short* hb1,
                            unsigned* cnt, unsigned* rel, unsigned* gcnt, unsigned* tqflag,
                            const float* V, float* vbound){
  int i = blockIdx.x * 256 + threadIdx.x;
  if (i < B_*U_){ c[i] = 0.f; hb0[i] = 0; hb1[i] = 0; }
  if (i < 64*16){ cnt[i] = 0u; rel[i] = 0u; gcnt[i] = 0u; tqflag[i] = 0u; }
  if (blockIdx.x == 0){
    __shared__ float red[4];
    int t = threadIdx.x, lane = t & 63, w = t >> 6;
    float s = fabsf(V[t]) + fabsf(V[t+256]) + fabsf(V[t+512]) + fabsf(V[t+768]);
    #pragma unroll
    for (int mk = 32; mk >= 1; mk >>= 1) s += __shfl_xor(s, mk, 64);
    if (lane == 0) red[w] = s;
    __syncthreads();
    if (t == 0) vbound[0] = red[0] + red[1] + red[2] + red[3];
  }
}

// ---------------- transpose + bf16 convert: W[K][N] -> WT[N][K] ----------------
__global__ void transpose_bf_kernel(const float* W, unsigned short* WT, int K, int N){
  int ktiles = K >> 5;
  int kb = blockIdx.x % ktiles, nb = blockIdx.x / ktiles;
  __shared__ float tile[32][33];
  int x = threadIdx.x & 31, y8 = threadIdx.x >> 5;
  #pragma unroll
  for (int i = 0; i < 4; ++i){
    int y = y8*4 + i;
    tile[y][x] = W[(size_t)(kb*32 + y)*N + nb*32 + x];
  }
  __syncthreads();
  #pragma unroll
  for (int i = 0; i < 4; ++i){
    int y = y8*4 + i;
    WT[(size_t)(nb*32 + y)*K + kb*32 + x] = f2bf(tile[x][y]);
  }
}

// ---------------- embedding GEMMs (once per launch) ----------------
template<int AF32>
__global__ __launch_bounds__(256) void gemm_embed(const void* Aptr, const unsigned short* BT,
                                                  const float* bias, unsigned short* Cout,
                                                  int K, int act){
  int nb = blockIdx.x & 15, mb = blockIdx.x >> 4;
  int lane = threadIdx.x & 63, w = threadIdx.x >> 6;
  int l15 = lane & 15, quad = lane >> 4;
  int m0 = mb*64 + w*16;
  int arow = m0 + l15;
  f32x4 acc[4];
  #pragma unroll
  for (int nt = 0; nt < 4; ++nt) acc[nt] = (f32x4){0.f,0.f,0.f,0.f};

  for (int k0 = 0; k0 < K; k0 += 32){
    int koff = k0 + quad*8;
    s16x8 a8;
    if (AF32){
      const float* ap = (const float*)Aptr + (size_t)arow*K + koff;
      f32x4 lo = *(const f32x4*)ap;
      f32x4 hi = *(const f32x4*)(ap + 4);
      a8[0]=(short)f2bf(lo[0]); a8[1]=(short)f2bf(lo[1]); a8[2]=(short)f2bf(lo[2]); a8[3]=(short)f2bf(lo[3]);
      a8[4]=(short)f2bf(hi[0]); a8[5]=(short)f2bf(hi[1]); a8[6]=(short)f2bf(hi[2]); a8[7]=(short)f2bf(hi[3]);
    } else {
      a8 = *(const s16x8*)((const unsigned short*)Aptr + (size_t)arow*K + koff);
    }
    #pragma unroll
    for (int nt = 0; nt < 4; ++nt){
      const unsigned short* bp = BT + (size_t)(nb*64 + nt*16 + l15)*K + koff;
      s16x8 b8 = *(const s16x8*)bp;
      acc[nt] = __builtin_amdgcn_mfma_f32_16x16x32_bf16(a8, b8, acc[nt], 0, 0, 0);
    }
  }
  #pragma unroll
  for (int nt = 0; nt < 4; ++nt){
    int col = nb*64 + nt*16 + l15;
    float bv = bias[col];
    #pragma unroll
    for (int r = 0; r < 4; ++r){
      int row = m0 + quad*4 + r;
      float v = acc[nt][r] + bv;
      v = (act == 0) ? fmaxf(v, 0.f) : fast_tanh(v);
      Cout[(size_t)row*U_ + col] = f2bf(v);
    }
  }
}

// ---------------- persistent sequential kernel ----------------
struct SeqP {
  const unsigned short *W1Tb, *WkTb, *WrTb, *tk, *xv;
  const float *b1, *bl, *V, *Wo, *bo, *vbound;
  float *tq, *ew, *c, *zh, *out_part, *out;
  unsigned short *ctxb, *hb0, *hb1;
  unsigned *cnt, *rel, *gcnt, *tqflag;
};

// Hierarchical flush-free global barrier (round-7 validated).
__device__ inline void gridbar(unsigned* cnt, unsigned* rel, unsigned barno){
  __syncthreads();
  if (threadIdx.x == 0)
    __hip_atomic_fetch_add(&cnt[(blockIdx.x & 63) * 16], 1u, __ATOMIC_RELAXED, __HIP_MEMORY_SCOPE_AGENT);
  if (blockIdx.x == 0){
    if (threadIdx.x < 64){
      const unsigned tgt = barno * G_;
      for (;;){
        unsigned v = __hip_atomic_load(&cnt[threadIdx.x * 16], __ATOMIC_RELAXED, __HIP_MEMORY_SCOPE_AGENT);
        #pragma unroll
        for (int mk = 32; mk >= 1; mk >>= 1) v += __shfl_xor(v, mk, 64);
        if (v >= tgt) break;
        __builtin_amdgcn_s_sleep(2);
      }
      __hip_atomic_store(&rel[threadIdx.x * 16], barno, __ATOMIC_RELAXED, __HIP_MEMORY_SCOPE_AGENT);
    }
  } else if (threadIdx.x == 0){
    unsigned* myrel = &rel[(blockIdx.x & 63) * 16];
    while (__hip_atomic_load(myrel, __ATOMIC_RELAXED, __HIP_MEMORY_SCOPE_AGENT) < barno)
      __builtin_amdgcn_s_sleep(4);
  }
  __syncthreads();
}

// 16-block group barrier (one 64B line per batch element).
__device__ inline void groupbar(unsigned* gcnt, int b, unsigned tgt){
  __syncthreads();
  if (threadIdx.x == 0){
    __hip_atomic_fetch_add(&gcnt[b*16], 1u, __ATOMIC_RELAXED, __HIP_MEMORY_SCOPE_AGENT);
    while (__hip_atomic_load(&gcnt[b*16], __ATOMIC_RELAXED, __HIP_MEMORY_SCOPE_AGENT) < tgt)
      __builtin_amdgcn_s_sleep(1);
  }
  __syncthreads();
}

__device__ inline void out_reduce(const SeqP& p, int b, int sidx, float* smem,
                                  int t, int lane, int w){
  float v = aldf(&p.out_part[b*256 + t]);
  #pragma unroll
  for (int mk = 32; mk >= 1; mk >>= 1) v += __shfl_xor(v, mk, 64);
  if (lane == 0) smem[w] = v;
  __syncthreads();
  if (t == 0) p.out[sidx*64 + b] = smem[0] + smem[1] + smem[2] + smem[3] + p.bo[0];
  __syncthreads();
}

__global__ __launch_bounds__(256, 4) void seq_kernel(SeqP p){
  const int bi = blockIdx.x;
  const int t  = threadIdx.x;
  const int lane = t & 63, w = t >> 6;
  const int l15 = lane & 15, quad = lane >> 4;
  const int b = bi >> 4, g = bi & 15;
  __shared__ __align__(16) unsigned short xvs[T_*64];  // 32 KB: this block's xv slice
  __shared__ __align__(16) float smem[1664];           // 6.6 KB phase scratch
  unsigned barno = 0;
  const float Mb = p.vbound[0];   // softmax shift bound: |score| < sum|V|

  u64* tqu  = (u64*)p.tq;
  u64* ewu  = (u64*)p.ew;
  u64* zhu  = (u64*)p.zh;
  u64* ctxu = (u64*)p.ctxb;

  // ---- one-time residency: xv slice -> LDS; tk rows -> VGPRs; V -> VGPRs ----
  {
    const unsigned short* xp0 = p.xv + (size_t)b*T_*U_ + g*64;
    int c8 = (t & 7) * 8;
    for (int r = t >> 3; r < T_; r += 32){
      s16x8 v = *(const s16x8*)(xp0 + (size_t)r*U_ + c8);
      *(s16x8*)&xvs[r*64 + c8] = v;
    }
  }
  s16x8 tk0[4], tk1[4];
  {
    const unsigned short* kp = p.tk + ((size_t)b*T_ + g*16 + w*4)*U_ + lane*16;
    #pragma unroll
    for (int rr = 0; rr < 4; ++rr){
      tk0[rr] = *(const s16x8*)(kp + (size_t)rr*U_);
      tk1[rr] = *(const s16x8*)(kp + (size_t)rr*U_ + 8);
    }
  }
  float Vv[16];
  #pragma unroll
  for (int i = 0; i < 16; i += 4) *(f32x4*)&Vv[i] = *(const f32x4*)(p.V + lane*16 + i);

  for (int step = 0; step < T_; ++step){
    const u64* hbRu = (const u64*)((step & 1) ? p.hb1 : p.hb0);
    u64*       hbWu = (u64*)((step & 1) ? p.hb0 : p.hb1);

    gridbar(p.cnt, p.rel, ++barno);   // h_{t-1}, out_part at L3

    // ---- Phase A: tq (blocks 0..63, flag on完成), zh (64..319), out-reduce (960..1023) ----
    if (bi < 64){
      int jcol = bi*16 + l15;
      int rbase = (w*16 + l15) << 8;           // row * 256 u64
      const unsigned short* bp = p.W1Tb + (size_t)jcol*U_;
      f32x4 acc = (f32x4){0.f,0.f,0.f,0.f};
      #pragma unroll 8
      for (int k = 0; k < U_; k += 32){
        s16x8 a8 = frag_ald(hbRu + rbase + ((k + quad*8) >> 2));
        s16x8 b8 = *(const s16x8*)(bp + k + quad*8);
        acc = __builtin_amdgcn_mfma_f32_16x16x32_bf16(a8, b8, acc, 0, 0, 0);
      }
      float bj = p.b1[jcol];
      float* tqs = smem;   // 16*68
      #pragma unroll
      for (int r = 0; r < 4; ++r)
        tqs[l15*68 + w*16 + quad*4 + r] = fast_tanh(acc[r] + bj);
      __syncthreads();
      if (t < 64){
        int ub64 = (t*U_ + bi*16) >> 1;        // float-pair index
        #pragma unroll
        for (int cc = 0; cc < 16; cc += 2){
          U64F2 x;
          x.f[0] = tqs[(cc+0)*68 + t];
          x.f[1] = tqs[(cc+1)*68 + t];
          ast64(tqu + ub64 + (cc >> 1), x.q);
        }
      }
      __syncthreads();   // drain tq stores (vmcnt(0) before s_barrier)
      if (t == 0)
        __hip_atomic_store(&p.tqflag[bi*16], (unsigned)(step + 1), __ATOMIC_RELAXED, __HIP_MEMORY_SCOPE_AGENT);
    } else if (bi < 320){
      int bz = bi - 64;    // 16 zh cols each over 256 blocks
      int rbase = (w*16 + l15) << 8;
      int jc0 = bz*16 + l15;
      const unsigned short* bp0 = p.WrTb + (size_t)jc0*U_;
      f32x4 acc0 = (f32x4){0.f,0.f,0.f,0.f};
      #pragma unroll 8
      for (int k = 0; k < U_; k += 32){
        s16x8 a8 = frag_ald(hbRu + rbase + ((k + quad*8) >> 2));
        acc0 = __builtin_amdgcn_mfma_f32_16x16x32_bf16(a8, *(const s16x8*)(bp0 + k + quad*8), acc0, 0, 0, 0);
      }
      float bl0 = p.bl[jc0];
      int brow = w*16 + quad*4;
      U64F2 x;
      int i0 = (jc0*64 + brow) >> 1;
      x.f[0] = acc0[0] + bl0; x.f[1] = acc0[1] + bl0; ast64(zhu + i0, x.q);
      x.f[0] = acc0[2] + bl0; x.f[1] = acc0[3] + bl0; ast64(zhu + i0 + 1, x.q);
    } else if (bi >= 960){
      if (step > 0) out_reduce(p, bi - 960, step - 1, smem, t, lane, w);
    }

    // ---- B1 gate: wait on the 64 tq producer flags (not on zh stragglers) ----
    if (w == 0){
      const unsigned tgt = (unsigned)(step + 1);
      for (;;){
        unsigned v = __hip_atomic_load(&p.tqflag[lane*16], __ATOMIC_RELAXED, __HIP_MEMORY_SCOPE_AGENT);
        if (__all((int)(v >= tgt))) break;
        __builtin_amdgcn_s_sleep(2);
      }
    }
    __syncthreads();

    // ---- Phase B1: ew for 16 t-rows of batch b, tk from REGISTERS ----
    {
      float tqv[16];
      int tqb = (b*U_ + lane*16) >> 1;
      #pragma unroll
      for (int i = 0; i < 8; ++i){
        U64F2 x; x.q = ald64(tqu + tqb + i);
        tqv[2*i] = x.f[0]; tqv[2*i+1] = x.f[1];
      }
      int trow = g*16 + w*4;
      float sr[4];
      #pragma unroll
      for (int rr = 0; rr < 4; ++rr){
        float s = 0.f;
        #pragma unroll
        for (int e = 0; e < 8; ++e){
          float kf = bf2f((unsigned short)tk0[rr][e]);
          float num = tqv[e] + kf;
          float den = fmaf(tqv[e], kf, 1.0f);
          s += Vv[e] * num * fast_rcp(den);
        }
        #pragma unroll
        for (int e = 0; e < 8; ++e){
          float kf = bf2f((unsigned short)tk1[rr][e]);
          float num = tqv[8+e] + kf;
          float den = fmaf(tqv[8+e], kf, 1.0f);
          s += Vv[8+e] * num * fast_rcp(den);
        }
        sr[rr] = s;
      }
      #pragma unroll
      for (int mk = 32; mk >= 1; mk >>= 1){
        #pragma unroll
        for (int rr = 0; rr < 4; ++rr) sr[rr] += __shfl_xor(sr[rr], mk, 64);
      }
      if (lane == 0){
        int eb = (b*T_ + trow) >> 1;
        #pragma unroll
        for (int j = 0; j < 2; ++j){
          U64F2 x;
          x.f[0] = __expf(sr[2*j]   - Mb);
          x.f[1] = __expf(sr[2*j+1] - Mb);
          ast64(ewu + eb + j, x.q);
        }
      }
    }

    groupbar(p.gcnt, b, (unsigned)(step + 1) * 16u);   // ew[b] complete within group

    // ---- Phase B2: denom + weighted ctx chunk (xv from LDS), 64 u's ----
    {
      float* ewL = smem;        // 256
      float* tmp = smem + 256;  // 16
      float* red = smem + 272;  // 16*16*4 = 1024
      if (t < 128){
        U64F2 x; x.q = ald64(ewu + b*128 + t);
        ewL[2*t] = x.f[0]; ewL[2*t+1] = x.f[1];
      }
      __syncthreads();
      float e = ewL[t];
      float sum = e;
      #pragma unroll
      for (int mk = 32; mk >= 1; mk >>= 1) sum += __shfl_xor(sum, mk, 64);
      if (lane == 0) tmp[w] = sum;
      __syncthreads();
      float rd = fast_rcp(tmp[0] + tmp[1] + tmp[2] + tmp[3]);

      int ui = t & 15, tgp = t >> 4;
      f32x4 a = (f32x4){0.f,0.f,0.f,0.f};
      #pragma unroll 4
      for (int t8 = tgp; t8 < T_; t8 += 16){
        float wg = ewL[t8];
        u16x4 x4 = *(const u16x4*)&xvs[t8*64 + ui*4];
        a[0] = fmaf(wg, bf2f(x4[0]), a[0]);
        a[1] = fmaf(wg, bf2f(x4[1]), a[1]);
        a[2] = fmaf(wg, bf2f(x4[2]), a[2]);
        a[3] = fmaf(wg, bf2f(x4[3]), a[3]);
      }
      *(f32x4*)&red[(tgp*16 + ui)*4] = a;
      __syncthreads();
      if (t < 16){
        f32x4 r = (f32x4){0.f,0.f,0.f,0.f};
        #pragma unroll
        for (int gg = 0; gg < 16; ++gg){
          f32x4 rr = *(f32x4*)&red[(gg*16 + t)*4];
          r[0]+=rr[0]; r[1]+=rr[1]; r[2]+=rr[2]; r[3]+=rr[3];
        }
        U64H4 cv;
        cv.h[0]=f2bf(r[0]*rd); cv.h[1]=f2bf(r[1]*rd); cv.h[2]=f2bf(r[2]*rd); cv.h[3]=f2bf(r[3]*rd);
        ast64(ctxu + b*256 + g*16 + t, cv.q);
      }
    }

    gridbar(p.cnt, p.rel, ++barno);   // ctx (and zh, long since) at L3

    // ---- Phase C: z = ctx@Wk + zh, LSTM update (blocks 0..255, 4 u's each) ----
    if (bi < 256){
      int ub = bi*4;
      int gate = l15 >> 2, uo = l15 & 3;
      int jcol = gate*U_ + ub + uo;
      int rbase = (w*16 + l15) << 8;
      const unsigned short* bp0 = p.WkTb + (size_t)jcol*U_;
      f32x4 acc = (f32x4){0.f,0.f,0.f,0.f};
      #pragma unroll 8
      for (int k = 0; k < U_; k += 32){
        s16x8 a8 = frag_ald(ctxu + rbase + ((k + quad*8) >> 2));
        acc = __builtin_amdgcn_mfma_f32_16x16x32_bf16(a8, *(const s16x8*)(bp0 + k + quad*8), acc, 0, 0, 0);
      }
      int brow = w*16 + quad*4;
      int zi0 = (jcol*64 + brow) >> 1;
      U64F2 z0, z1;
      z0.q = ald64(zhu + zi0); z1.q = ald64(zhu + zi0 + 1);
      acc[0] += z0.f[0]; acc[1] += z0.f[1]; acc[2] += z1.f[0]; acc[3] += z1.f[1];
      float* zs = smem;          // 16*68 = 1088
      float* hs = smem + 1088;   // 256
      float* op = smem + 1344;   // 256
      *(f32x4*)&zs[l15*68 + brow] = acc;
      __syncthreads();
      {
        int bb = t & 63, ui = t >> 6;   // ui in 0..3
        int u = ub + ui;
        float zi = zs[(0*4 + ui)*68 + bb];
        float zf = zs[(1*4 + ui)*68 + bb];
        float zg = zs[(2*4 + ui)*68 + bb];
        float zo = zs[(3*4 + ui)*68 + bb];
        float ig = fast_sig(zi), fg = fast_sig(zf);
        float gg = fast_tanh(zg), og = fast_sig(zo);
        float cold = p.c[u*64 + bb];   // block-private across steps
        float cn = fg*cold + ig*gg;
        float hn = og * fast_tanh(cn);
        p.c[u*64 + bb] = cn;
        hs[ui*64 + bb] = hn;
        op[ui*64 + bb] = hn * p.Wo[u];
      }
      __syncthreads();
      if (t < 64){
        U64H4 h0;
        #pragma unroll
        for (int k = 0; k < 4; ++k) h0.h[k] = f2bf(hs[k*64 + t]);
        ast64(hbWu + t*256 + bi, h0.q);
        float po = op[t] + op[64 + t] + op[128 + t] + op[192 + t];
        astf(&p.out_part[t*256 + bi], po);
      }
    }
  }

  gridbar(p.cnt, p.rel, ++barno);   // final out_part at L3
  if (bi >= 960) out_reduce(p, bi - 960, T_ - 1, smem, t, lane, w);
}

extern "C" void kernel_launch(void* const* d_in, const int* in_sizes, int n_in,
                              void* d_out, int out_size, void* d_ws, size_t ws_size,
                              hipStream_t stream){
  const float* inputs = (const float*)d_in[0];
  const float* We1 = (const float*)d_in[1];
  const float* be1 = (const float*)d_in[2];
  const float* We2 = (const float*)d_in[3];
  const float* be2 = (const float*)d_in[4];
  const float* W1  = (const float*)d_in[5];
  const float* b1  = (const float*)d_in[6];
  const float* W2  = (const float*)d_in[7];
  const float* b2  = (const float*)d_in[8];
  const float* V   = (const float*)d_in[9];
  // d_in[10] = bV: softmax shift-invariant, dropped
  const float* Wk  = (const float*)d_in[11];
  const float* Wr  = (const float*)d_in[12];
  const float* bl  = (const float*)d_in[13];
  const float* Wo  = (const float*)d_in[14];
  const float* bo  = (const float*)d_in[15];
  float* out = (float*)d_out;

  char* ws = (char*)d_ws;
  size_t off = 0;
  auto alloc = [&](size_t bytes) -> void* {
    void* pp = ws + off;
    off = (off + bytes + 255) & ~(size_t)255;
    return pp;
  };
  // h1 (GEMM-1 output) is dead after GEMM-2; tk (GEMM-3 output) aliases it.
  unsigned short* We1Tb = (unsigned short*)alloc((size_t)1024*128*2);
  unsigned short* We2Tb = (unsigned short*)alloc((size_t)1024*1024*2);
  unsigned short* W2Tb  = (unsigned short*)alloc((size_t)1024*1024*2);
  unsigned short* W1Tb  = (unsigned short*)alloc((size_t)1024*1024*2);
  unsigned short* WkTb  = (unsigned short*)alloc((size_t)4096*1024*2);
  unsigned short* WrTb  = (unsigned short*)alloc((size_t)4096*1024*2);
  unsigned short* h1tk  = (unsigned short*)alloc((size_t)BT_*U_*2);  // h1, then tk
  unsigned short* xv    = (unsigned short*)alloc((size_t)BT_*U_*2);
  float*          c     = (float*)alloc((size_t)B_*U_*4);
  unsigned short* hb0   = (unsigned short*)alloc((size_t)B_*U_*2);
  unsigned short* hb1   = (unsigned short*)alloc((size_t)B_*U_*2);
  unsigned short* ctxb  = (unsigned short*)alloc((size_t)B_*U_*2);
  float*          tq    = (float*)alloc((size_t)B_*U_*4);
  float*          ew    = (float*)alloc((size_t)B_*T_*4);
  float*          zh    = (float*)alloc((size_t)4*U_*64*4);
  float*          out_part = (float*)alloc((size_t)64*256*4);
  unsigned*       cnt   = (unsigned*)alloc(64*16*4);
  unsigned*       rel   = (unsigned*)alloc(64*16*4);
  unsigned*       gcnt  = (unsigned*)alloc(64*16*4);
  unsigned*       tqflag= (unsigned*)alloc(64*16*4);
  float*          vbound= (float*)alloc(256);
  if (ws_size < off) return;  // workspace too small: fail loudly (validation mismatch)

  init_kernel<<<256, 256, 0, stream>>>(c, hb0, hb1, cnt, rel, gcnt, tqflag, V, vbound);
  transpose_bf_kernel<<<(128/32)*(1024/32),  256, 0, stream>>>(We1, We1Tb, 128, 1024);
  transpose_bf_kernel<<<(1024/32)*(1024/32), 256, 0, stream>>>(We2, We2Tb, 1024, 1024);
  transpose_bf_kernel<<<(1024/32)*(1024/32), 256, 0, stream>>>(W2,  W2Tb,  1024, 1024);
  transpose_bf_kernel<<<(1024/32)*(1024/32), 256, 0, stream>>>(W1,  W1Tb,  1024, 1024);
  transpose_bf_kernel<<<(1024/32)*(4096/32), 256, 0, stream>>>(Wk,  WkTb,  1024, 4096);
  transpose_bf_kernel<<<(1024/32)*(4096/32), 256, 0, stream>>>(Wr,  WrTb,  1024, 4096);

  gemm_embed<1><<<4096, 256, 0, stream>>>((const void*)inputs, We1Tb, be1, h1tk, DIN_, 0);
  gemm_embed<0><<<4096, 256, 0, stream>>>((const void*)h1tk,   We2Tb, be2, xv,   U_,   0);
  gemm_embed<0><<<4096, 256, 0, stream>>>((const void*)xv,     W2Tb,  b2,  h1tk, U_,   1);

  SeqP sp;
  sp.W1Tb = W1Tb; sp.WkTb = WkTb; sp.WrTb = WrTb; sp.tk = h1tk; sp.xv = xv;
  sp.b1 = b1; sp.bl = bl; sp.V = V; sp.Wo = Wo; sp.bo = bo; sp.vbound = vbound;
  sp.tq = tq; sp.ew = ew; sp.c = c; sp.zh = zh;
  sp.out_part = out_part; sp.out = out;
  sp.ctxb = ctxb; sp.hb0 = hb0; sp.hb1 = hb1; sp.cnt = cnt; sp.rel = rel;
  sp.gcnt = gcnt; sp.tqflag = tqflag;
  seq_kernel<<<dim3(G_), dim3(256), 0, stream>>>(sp);
}